// Round 1
// baseline (209.194 us; speedup 1.0000x reference)
//
#include <hip/hip_runtime.h>

#define BB 2
#define HH 56
#define WW 56
#define NN 2
#define CC 128
#define NH 8
#define DD 16
#define WSP 7
#define L 784            // tokens per window = 56*7*2
#define ROWS_PER_BLOCK 196
#define CHUNK 56

// ---------------- Kernel 1: RPE (depthwise conv + self-scaled term) --------
__global__ __launch_bounds__(256) void rpe_kernel(const float* __restrict__ value,
                                                  const float* __restrict__ conv_w,
                                                  float* __restrict__ out) {
    int idx = blockIdx.x * blockDim.x + threadIdx.x; // over B*H*W*C
    if (idx >= BB * HH * WW * CC) return;
    int c = idx & (CC - 1);
    int t = idx >> 7;          // b*H*W + y*W + x
    int x = t % WW;
    int t2 = t / WW;
    int y = t2 % HH;
    int b = t2 / HH;

    float w[9];
#pragma unroll
    for (int k = 0; k < 9; ++k) w[k] = conv_w[c * 9 + k];

    float conv_sum = 0.f;
#pragma unroll
    for (int dy = -1; dy <= 1; ++dy) {
        int yy = y + dy;
        if (yy < 0 || yy >= HH) continue;
#pragma unroll
        for (int dx = -1; dx <= 1; ++dx) {
            int xx = x + dx;
            if (xx < 0 || xx >= WW) continue;
            const float* p = value + (((long)(b * HH + yy) * WW + xx) * NN) * CC + c;
            float vs = p[0] + p[CC];   // sum over n
            conv_sum += w[(dy + 1) * 3 + (dx + 1)] * vs;
        }
    }
    float center = w[4];
    const float* pc = value + (((long)(b * HH + y) * WW + x) * NN) * CC + c;
    float v0 = pc[0], v1 = pc[CC];
    float base = conv_sum - center * (v0 + v1);
    float* po = out + (((long)(b * HH + y) * WW + x) * NN) * CC + c;
    po[0]  = base + center * v0;
    po[CC] = base + center * v1;
}

// ---------------- Kernel 2: windowed attention (flash-style, f32) ----------
// grid: (4 row-blocks, 8 heads, 16 windows); block: 256 threads.
__global__ __launch_bounds__(256) void attn_kernel(const float* __restrict__ q_g,
                                                   const float* __restrict__ k_g,
                                                   const float* __restrict__ v_g,
                                                   float* __restrict__ out) {
    __shared__ float Kl[CHUNK][DD];
    __shared__ float Vl[CHUNK][DD];

    const int rb  = blockIdx.x;       // 0..3
    const int hh  = blockIdx.y;       // 0..7
    const int win = blockIdx.z;       // 0..15
    const int b   = win >> 3;
    const int wj  = win & 7;
    const int tid = threadIdx.x;

    const int r = rb * ROWS_PER_BLOCK + tid;   // query row in window
    const bool active = tid < ROWS_PER_BLOCK;

    float q[DD];
    float acc[DD];
    float m = -1e30f, l = 0.f;
    long tokbase = 0;

    if (active) {
        int pos = r >> 1, n = r & 1;
        int y = pos / WSP, wx = pos % WSP;
        tokbase = (((long)(b * HH + y) * WW + (wj * WSP + wx)) * NN + n) * CC + hh * DD;
#pragma unroll
        for (int d = 0; d < DD; ++d) {
            q[d] = q_g[tokbase + d] * 0.25f;   // scale = d^-0.5 = 1/4
            acc[d] = 0.f;
        }
    }

    for (int c0 = 0; c0 < L / CHUNK; ++c0) {
        const int j0 = c0 * CHUNK;
        __syncthreads();
        // stage CHUNK tokens of K and V: 56*16 floats = 224 float4 each
        if (tid < CHUNK * DD / 4) {
            int tok = tid >> 2;
            int d4  = (tid & 3) * 4;
            int j = j0 + tok;
            int pos = j >> 1, n = j & 1;
            int y = pos / WSP, wx = pos % WSP;
            long off = (((long)(b * HH + y) * WW + (wj * WSP + wx)) * NN + n) * CC + hh * DD + d4;
            float4 kv = *(const float4*)(k_g + off);
            float4 vv = *(const float4*)(v_g + off);
            *(float4*)&Kl[tok][d4] = kv;
            *(float4*)&Vl[tok][d4] = vv;
        }
        __syncthreads();

        if (active) {
            float s[CHUNK];
            float cmax = -1e30f;
#pragma unroll
            for (int jj = 0; jj < CHUNK; ++jj) {
                const float4* kp = (const float4*)&Kl[jj][0];
                float4 k0 = kp[0], k1 = kp[1], k2 = kp[2], k3 = kp[3];
                float acc_s = q[0] * k0.x + q[1] * k0.y + q[2] * k0.z + q[3] * k0.w
                            + q[4] * k1.x + q[5] * k1.y + q[6] * k1.z + q[7] * k1.w
                            + q[8] * k2.x + q[9] * k2.y + q[10] * k2.z + q[11] * k2.w
                            + q[12] * k3.x + q[13] * k3.y + q[14] * k3.z + q[15] * k3.w;
                if (j0 + jj == (r ^ 1)) acc_s = -1e30f;   // sibling mask
                s[jj] = acc_s;
                cmax = fmaxf(cmax, acc_s);
            }
            float mnew = fmaxf(m, cmax);
            float f = __expf(m - mnew);
            l *= f;
#pragma unroll
            for (int d = 0; d < DD; ++d) acc[d] *= f;
#pragma unroll
            for (int jj = 0; jj < CHUNK; ++jj) {
                float p = __expf(s[jj] - mnew);
                l += p;
                const float4* vp = (const float4*)&Vl[jj][0];
                float4 v0 = vp[0], v1 = vp[1], v2 = vp[2], v3 = vp[3];
                acc[0]  += p * v0.x;  acc[1]  += p * v0.y;  acc[2]  += p * v0.z;  acc[3]  += p * v0.w;
                acc[4]  += p * v1.x;  acc[5]  += p * v1.y;  acc[6]  += p * v1.z;  acc[7]  += p * v1.w;
                acc[8]  += p * v2.x;  acc[9]  += p * v2.y;  acc[10] += p * v2.z;  acc[11] += p * v2.w;
                acc[12] += p * v3.x;  acc[13] += p * v3.y;  acc[14] += p * v3.z;  acc[15] += p * v3.w;
            }
            m = mnew;
        }
    }

    if (active) {
        float inv = 1.f / l;
        float* po = out + tokbase;
#pragma unroll
        for (int d = 0; d < DD; ++d) po[d] = po[d] + acc[d] * inv;  // += RPE already there
    }
}

extern "C" void kernel_launch(void* const* d_in, const int* in_sizes, int n_in,
                              void* d_out, int out_size, void* d_ws, size_t ws_size,
                              hipStream_t stream) {
    const float* q = (const float*)d_in[0];
    const float* k = (const float*)d_in[1];
    const float* v = (const float*)d_in[2];
    const float* w = (const float*)d_in[3];
    float* out = (float*)d_out;

    int n1 = BB * HH * WW * CC;
    rpe_kernel<<<(n1 + 255) / 256, 256, 0, stream>>>(v, w, out);

    dim3 grid(4, NH, 16);
    attn_kernel<<<grid, 256, 0, stream>>>(q, k, v, out);
}

// Round 2
// 86.027 us; speedup vs baseline: 2.4317x; 2.4317x over previous
//
#include <hip/hip_runtime.h>

typedef __bf16 bf16x8 __attribute__((ext_vector_type(8)));
typedef float f32x16 __attribute__((ext_vector_type(16)));

#define BB 2
#define HH 56
#define WW 56
#define NN 2
#define CC 128
#define NH 8
#define DD 16
#define WSP 7
#define LQ 784           // tokens per window = 56*7*2
#define QT 32            // queries per wave
#define NQT 25           // ceil(784/32)
#define KC 32            // keys per chunk
#define NKC 25

static __device__ __forceinline__ unsigned short f2bf(float f) {
    unsigned u = __builtin_bit_cast(unsigned, f);
    return (unsigned short)((u + 0x7FFFu + ((u >> 16) & 1u)) >> 16);
}
static __device__ __forceinline__ unsigned pack2(float a, float b) {
    return (unsigned)f2bf(a) | ((unsigned)f2bf(b) << 16);
}

// ---------------- Kernel 1: RPE (depthwise conv + self-scaled term) --------
__global__ __launch_bounds__(256) void rpe_kernel(const float* __restrict__ value,
                                                  const float* __restrict__ conv_w,
                                                  float* __restrict__ out) {
    int idx = blockIdx.x * blockDim.x + threadIdx.x; // over B*H*W*C
    if (idx >= BB * HH * WW * CC) return;
    int c = idx & (CC - 1);
    int t = idx >> 7;          // b*H*W + y*W + x
    int x = t % WW;
    int t2 = t / WW;
    int y = t2 % HH;
    int b = t2 / HH;

    float w[9];
#pragma unroll
    for (int k = 0; k < 9; ++k) w[k] = conv_w[c * 9 + k];

    float conv_sum = 0.f;
#pragma unroll
    for (int dy = -1; dy <= 1; ++dy) {
        int yy = y + dy;
        if (yy < 0 || yy >= HH) continue;
#pragma unroll
        for (int dx = -1; dx <= 1; ++dx) {
            int xx = x + dx;
            if (xx < 0 || xx >= WW) continue;
            const float* p = value + (((long)(b * HH + yy) * WW + xx) * NN) * CC + c;
            float vs = p[0] + p[CC];   // sum over n
            conv_sum += w[(dy + 1) * 3 + (dx + 1)] * vs;
        }
    }
    float center = w[4];
    const float* pc = value + (((long)(b * HH + y) * WW + x) * NN) * CC + c;
    float v0 = pc[0], v1 = pc[CC];
    float base = conv_sum - center * (v0 + v1);
    float* po = out + (((long)(b * HH + y) * WW + x) * NN) * CC + c;
    po[0]  = base + center * v0;
    po[CC] = base + center * v1;
}

// ---------------- Kernel 2: MFMA flash attention -----------------------
// One wave per (Q-tile of 32 rows, head, window). Swapped QK^T:
//   S^T = mfma(A=K, B=Q)  -> lane owns query col (lane&31); softmax lane-local.
//   O^T = mfma(A=V^T, B=P) accumulated; D row = d (regs 0..7 valid).
__global__ __launch_bounds__(64) void attn_mfma(const float* __restrict__ q_g,
                                                const float* __restrict__ k_g,
                                                const float* __restrict__ v_g,
                                                float* __restrict__ out) {
    __shared__ int taddr[800];

    const int lane = threadIdx.x;      // 0..63
    const int col  = lane & 31;        // query col (S,O) / key row (K-frag) / d row (V-frag)
    const int h    = lane >> 5;
    const int head = blockIdx.y;
    const int win  = blockIdx.z;
    const int b    = win >> 3;
    const int wj   = win & 7;
    const int q0   = blockIdx.x * QT;

    // token address table (element offsets into the f32 tensors, incl. head base)
    for (int idx = lane; idx < 800; idx += 64) {
        int rc = idx < LQ ? idx : LQ - 1;
        int pos = rc >> 1, n = rc & 1;
        int y = pos / WSP, xl = pos - y * WSP;
        taddr[idx] = (((b * HH + y) * WW + (wj * WSP + xl)) * NN + n) * CC + head * DD;
    }
    __syncthreads();

    union U4 { unsigned u[4]; bf16x8 v; };

    // Q fragment (B operand): col=query=lane&31, k=d=(lane>>5)*8+i
    U4 qf;
    {
        const float* qp = q_g + taddr[q0 + col] + h * 8;
        float4 a0 = *(const float4*)qp;
        float4 a1 = *(const float4*)(qp + 4);
        qf.u[0] = pack2(a0.x * 0.25f, a0.y * 0.25f);   // scale = d^-0.5 = 1/4
        qf.u[1] = pack2(a0.z * 0.25f, a0.w * 0.25f);
        qf.u[2] = pack2(a1.x * 0.25f, a1.y * 0.25f);
        qf.u[3] = pack2(a1.z * 0.25f, a1.w * 0.25f);
    }

    f32x16 acc;
#pragma unroll
    for (int i = 0; i < 16; ++i) acc[i] = 0.f;
    float m = -1e30f, lsum = 0.f;

    const int myq = q0 + col;
    const int sib = myq ^ 1;           // sibling token (same pos, other n)
    const int dl  = col & 15;

    for (int c = 0; c < NKC; ++c) {
        const int j0 = c * KC;

        // K fragment (A operand): row=key=lane&31, k=d
        U4 kf;
        {
            const float* kp = k_g + taddr[j0 + col] + h * 8;
            float4 a0 = *(const float4*)kp;
            float4 a1 = *(const float4*)(kp + 4);
            kf.u[0] = pack2(a0.x, a0.y);
            kf.u[1] = pack2(a0.z, a0.w);
            kf.u[2] = pack2(a1.x, a1.y);
            kf.u[3] = pack2(a1.z, a1.w);
        }

        f32x16 z;
#pragma unroll
        for (int i = 0; i < 16; ++i) z[i] = 0.f;
        // S^T tile: row=key=(reg&3)+8*(reg>>2)+4h, col=query=lane&31
        f32x16 st = __builtin_amdgcn_mfma_f32_32x32x16_bf16(kf.v, qf.v, z, 0, 0, 0);

        float p[16];
        float cmax = -1e30f;
#pragma unroll
        for (int r = 0; r < 16; ++r) {
            int kr = (r & 3) + 8 * (r >> 2) + 4 * h;   // key within chunk
            float sv = st[r];
            int gk = j0 + kr;
            if (gk >= LQ || gk == sib) sv = -1e30f;
            p[r] = sv;
            cmax = fmaxf(cmax, sv);
        }
        cmax = fmaxf(cmax, __shfl_xor(cmax, 32, 64));   // other half's 16 keys
        float mnew = fmaxf(m, cmax);
        float fs = __expf(m - mnew);
        float psum = 0.f;
#pragma unroll
        for (int r = 0; r < 16; ++r) {
            p[r] = __expf(p[r] - mnew);
            psum += p[r];
        }
        psum += __shfl_xor(psum, 32, 64);
        lsum = lsum * fs + psum;
        m = mnew;
#pragma unroll
        for (int r = 0; r < 8; ++r) acc[r] *= fs;       // only d<16 regs matter

        // pack P to bf16 pairs; swap halves so each lane can build B-frags
        // pk[b2][e] covers keys (8*b2 + 4*h + 2e, +1) of this chunk
        unsigned pk[4][2], sw[4][2];
#pragma unroll
        for (int b2 = 0; b2 < 4; ++b2) {
            pk[b2][0] = pack2(p[4 * b2 + 0], p[4 * b2 + 1]);
            pk[b2][1] = pack2(p[4 * b2 + 2], p[4 * b2 + 3]);
            sw[b2][0] = __shfl_xor(pk[b2][0], 32, 64);
            sw[b2][1] = __shfl_xor(pk[b2][1], 32, 64);
        }

#pragma unroll
        for (int t = 0; t < 2; ++t) {
            // B = P fragment: col=query=lane&31, k = keys 16t+8h+0..7
            U4 pb;
            pb.u[0] = h ? sw[2 * t + 1][0] : pk[2 * t][0];
            pb.u[1] = h ? sw[2 * t + 1][1] : pk[2 * t][1];
            pb.u[2] = h ? pk[2 * t + 1][0] : sw[2 * t][0];
            pb.u[3] = h ? pk[2 * t + 1][1] : sw[2 * t][1];

            // A = V^T fragment: row=d'=lane&31 (d<16 valid), k = keys 16t+8h+0..7
            U4 vf;
            float vv[8];
#pragma unroll
            for (int i = 0; i < 8; ++i) {
                vv[i] = v_g[taddr[j0 + 16 * t + 8 * h + i] + dl];
            }
            vf.u[0] = pack2(vv[0], vv[1]);
            vf.u[1] = pack2(vv[2], vv[3]);
            vf.u[2] = pack2(vv[4], vv[5]);
            vf.u[3] = pack2(vv[6], vv[7]);

            acc = __builtin_amdgcn_mfma_f32_32x32x16_bf16(vf.v, pb.v, acc, 0, 0, 0);
        }
    }

    // writeout: O^T reg layout: d = (reg&3)+8*(reg>>2)+4h for reg 0..7
    if (myq < LQ) {
        float inv = 1.f / lsum;
        float* po = out + taddr[myq];
#pragma unroll
        for (int r = 0; r < 8; ++r) {
            int d = (r & 3) + 8 * (r >> 2) + 4 * h;
            po[d] += acc[r] * inv;     // += RPE already written there
        }
    }
}

extern "C" void kernel_launch(void* const* d_in, const int* in_sizes, int n_in,
                              void* d_out, int out_size, void* d_ws, size_t ws_size,
                              hipStream_t stream) {
    const float* q = (const float*)d_in[0];
    const float* k = (const float*)d_in[1];
    const float* v = (const float*)d_in[2];
    const float* w = (const float*)d_in[3];
    float* out = (float*)d_out;

    int n1 = BB * HH * WW * CC;
    rpe_kernel<<<(n1 + 255) / 256, 256, 0, stream>>>(v, w, out);

    dim3 grid(NQT, NH, 16);
    attn_mfma<<<grid, 64, 0, stream>>>(q, k, v, out);
}

// Round 3
// 65.795 us; speedup vs baseline: 3.1795x; 1.3075x over previous
//
#include <hip/hip_runtime.h>

typedef __bf16 bf16x8 __attribute__((ext_vector_type(8)));
typedef float f32x16 __attribute__((ext_vector_type(16)));

#define BB 2
#define HH 56
#define WW 56
#define NN 2
#define CC 128
#define NH 8
#define DD 16
#define WSP 7
#define LQ 784           // tokens per window = 56*7*2
#define NQT 25           // Q tiles of 32
#define NKC 25           // K chunks of 32
#define NINST 128        // 16 windows * 8 heads
#define VTP 800          // padded token stride for V^T rows

union U2 { __bf16 h[2]; unsigned u; };
union U4 { unsigned u[4]; bf16x8 v; };
union H8 { bf16x8 v; uint4 q; };

// ---------------- Kernel 1: RPE (depthwise conv + self-scaled term) --------
__global__ __launch_bounds__(256) void rpe_kernel(const float* __restrict__ value,
                                                  const float* __restrict__ conv_w,
                                                  float* __restrict__ out) {
    int idx = blockIdx.x * blockDim.x + threadIdx.x; // over B*H*W*C
    if (idx >= BB * HH * WW * CC) return;
    int c = idx & (CC - 1);
    int t = idx >> 7;          // b*H*W + y*W + x
    int x = t % WW;
    int t2 = t / WW;
    int y = t2 % HH;
    int b = t2 / HH;

    float w[9];
#pragma unroll
    for (int k = 0; k < 9; ++k) w[k] = conv_w[c * 9 + k];

    float conv_sum = 0.f;
#pragma unroll
    for (int dy = -1; dy <= 1; ++dy) {
        int yy = y + dy;
        if (yy < 0 || yy >= HH) continue;
#pragma unroll
        for (int dx = -1; dx <= 1; ++dx) {
            int xx = x + dx;
            if (xx < 0 || xx >= WW) continue;
            const float* p = value + (((long)(b * HH + yy) * WW + xx) * NN) * CC + c;
            float vs = p[0] + p[CC];   // sum over n
            conv_sum += w[(dy + 1) * 3 + (dx + 1)] * vs;
        }
    }
    float center = w[4];
    const float* pc = value + (((long)(b * HH + y) * WW + x) * NN) * CC + c;
    float v0 = pc[0], v1 = pc[CC];
    float base = conv_sum - center * (v0 + v1);
    float* po = out + (((long)(b * HH + y) * WW + x) * NN) * CC + c;
    po[0]  = base + center * v0;
    po[CC] = base + center * v1;
}

// ---------------- Kernel 2: pack K (bf16, [inst][tok][16]) and V^T ---------
// (bf16, [inst][d][tok padded to 800]) into workspace. One thread per
// (inst, tok); fully coalesced reads and writes.
__global__ __launch_bounds__(256) void pack_kv(const float* __restrict__ k_g,
                                               const float* __restrict__ v_g,
                                               __bf16* __restrict__ kb,
                                               __bf16* __restrict__ vt) {
    int idx = blockIdx.x * blockDim.x + threadIdx.x;
    if (idx >= NINST * LQ) return;
    int inst = idx / LQ;
    int tok  = idx - inst * LQ;
    int head = inst & 7, win = inst >> 3;
    int b = win >> 3, wj = win & 7;
    int pos = tok >> 1, n = tok & 1;
    int y = pos / WSP, xl = pos - y * WSP;
    long off = ((long)(((b * HH + y) * WW + wj * WSP + xl) * NN + n)) * CC + head * DD;

    float kv[16], vv[16];
    *(float4*)&kv[0]  = *(const float4*)(k_g + off);
    *(float4*)&kv[4]  = *(const float4*)(k_g + off + 4);
    *(float4*)&kv[8]  = *(const float4*)(k_g + off + 8);
    *(float4*)&kv[12] = *(const float4*)(k_g + off + 12);
    *(float4*)&vv[0]  = *(const float4*)(v_g + off);
    *(float4*)&vv[4]  = *(const float4*)(v_g + off + 4);
    *(float4*)&vv[8]  = *(const float4*)(v_g + off + 8);
    *(float4*)&vv[12] = *(const float4*)(v_g + off + 12);

    H8 lo, hi;
#pragma unroll
    for (int i = 0; i < 8; ++i) { lo.v[i] = (__bf16)kv[i]; hi.v[i] = (__bf16)kv[8 + i]; }
    uint4* kq = (uint4*)kb + (long)idx * 2;
    kq[0] = lo.q;
    kq[1] = hi.q;

#pragma unroll
    for (int d = 0; d < 16; ++d)
        vt[((long)inst * 16 + d) * VTP + tok] = (__bf16)vv[d];
}

// ---------------- Kernel 3: MFMA flash attention ---------------------------
// One wave per (32-query tile, head, window). Swapped QK^T:
//   S^T = mfma(A=K, B=Q)  -> lane owns query col (lane&31); softmax lane-local.
//   O^T = mfma(A=V^T, B=P) accumulated; regs 0..7 hold d = (r&3)+8*(r>>2)+4h.
__global__ __launch_bounds__(64) void attn_mfma(const float* __restrict__ q_g,
                                                const __bf16* __restrict__ kb,
                                                const __bf16* __restrict__ vt,
                                                float* __restrict__ out) {
    const int lane = threadIdx.x;
    const int col  = lane & 31;        // query col / key row / d row
    const int h    = lane >> 5;
    const int dl   = col & 15;
    const int head = blockIdx.y;
    const int win  = blockIdx.z;
    const int inst = win * 8 + head;
    const int qt   = blockIdx.x;
    const int q0   = qt * 32;
    const int myq  = q0 + col;
    const int sib  = myq ^ 1;

    // output/query address in original layout
    const int myqc = myq < LQ ? myq : LQ - 1;
    const int b = win >> 3, wj = win & 7;
    const int pos = myqc >> 1, n = myqc & 1;
    const int y = pos / WSP, xl = pos - y * WSP;
    const long ooff = ((long)(((b * HH + y) * WW + wj * WSP + xl) * NN + n)) * CC + head * DD;

    // Q fragment (B operand): col=query, k = d = 8h..8h+7; fold in scale 1/4
    bf16x8 qfv;
    {
        const float* qp = q_g + ooff + 8 * h;
        float qv[8];
        *(float4*)&qv[0] = *(const float4*)qp;
        *(float4*)&qv[4] = *(const float4*)(qp + 4);
        H8 qq;
#pragma unroll
        for (int i = 0; i < 8; ++i) qq.v[i] = (__bf16)(qv[i] * 0.25f);
        qfv = qq.v;
    }

    f32x16 acc, zv;
#pragma unroll
    for (int i = 0; i < 16; ++i) { acc[i] = 0.f; zv[i] = 0.f; }
    float m = -1e30f, lsum = 0.f;

    const bf16x8* kp = (const bf16x8*)kb + ((long)inst * LQ + col) * 2 + h;
    const __bf16* vp = vt + ((long)inst * 16 + dl) * VTP + 8 * h;

    for (int c = 0; c < NKC; ++c) {
        const int j0 = c * 32;
        bf16x8 kf = *kp;
        kp += 64;                       // 32 tokens * 2 fragments

        f32x16 st = __builtin_amdgcn_mfma_f32_32x32x16_bf16(kf, qfv, zv, 0, 0, 0);

        float p[16];
        float cmax = -1e30f;
        if (c == qt || c == NKC - 1) {  // only these chunks need masking
#pragma unroll
            for (int r = 0; r < 16; ++r) {
                int kr = (r & 3) + 8 * (r >> 2) + 4 * h;
                int gk = j0 + kr;
                float sv = st[r];
                if (gk >= LQ || gk == sib) sv = -1e30f;
                p[r] = sv;
                cmax = fmaxf(cmax, sv);
            }
        } else {
#pragma unroll
            for (int r = 0; r < 16; ++r) {
                p[r] = st[r];
                cmax = fmaxf(cmax, st[r]);
            }
        }
        cmax = fmaxf(cmax, __shfl_xor(cmax, 32, 64));
        float mnew = fmaxf(m, cmax);
        float fs = __expf(m - mnew);
        float psum = 0.f;
#pragma unroll
        for (int r = 0; r < 16; ++r) {
            p[r] = __expf(p[r] - mnew);
            psum += p[r];
        }
        psum += __shfl_xor(psum, 32, 64);
        lsum = lsum * fs + psum;
        m = mnew;
#pragma unroll
        for (int r = 0; r < 8; ++r) acc[r] *= fs;   // only d<16 regs matter

        // pack P to bf16 pairs; swap halves so each lane builds its B-frag
        unsigned pk[4][2], sw[4][2];
#pragma unroll
        for (int b2 = 0; b2 < 4; ++b2) {
            U2 a, bb;
            a.h[0]  = (__bf16)p[4 * b2 + 0];
            a.h[1]  = (__bf16)p[4 * b2 + 1];
            bb.h[0] = (__bf16)p[4 * b2 + 2];
            bb.h[1] = (__bf16)p[4 * b2 + 3];
            pk[b2][0] = a.u;
            pk[b2][1] = bb.u;
            sw[b2][0] = __shfl_xor(pk[b2][0], 32, 64);
            sw[b2][1] = __shfl_xor(pk[b2][1], 32, 64);
        }

#pragma unroll
        for (int t = 0; t < 2; ++t) {
            U4 pb;
            pb.u[0] = h ? sw[2 * t + 1][0] : pk[2 * t][0];
            pb.u[1] = h ? sw[2 * t + 1][1] : pk[2 * t][1];
            pb.u[2] = h ? pk[2 * t + 1][0] : sw[2 * t][0];
            pb.u[3] = h ? pk[2 * t + 1][1] : sw[2 * t][1];

            bf16x8 vf = *(const bf16x8*)(vp + j0 + 16 * t);
            acc = __builtin_amdgcn_mfma_f32_32x32x16_bf16(vf, pb.v, acc, 0, 0, 0);
        }
    }

    if (myq < LQ) {
        float inv = 1.f / lsum;
        float* po = out + ooff;
#pragma unroll
        for (int r = 0; r < 8; ++r) {
            int d = (r & 3) + 8 * (r >> 2) + 4 * h;
            po[d] += acc[r] * inv;     // += RPE already written there
        }
    }
}

extern "C" void kernel_launch(void* const* d_in, const int* in_sizes, int n_in,
                              void* d_out, int out_size, void* d_ws, size_t ws_size,
                              hipStream_t stream) {
    const float* q = (const float*)d_in[0];
    const float* k = (const float*)d_in[1];
    const float* v = (const float*)d_in[2];
    const float* w = (const float*)d_in[3];
    float* out = (float*)d_out;

    __bf16* kb = (__bf16*)d_ws;                       // 128*784*16 bf16 = 3.2 MB
    __bf16* vt = kb + (long)NINST * LQ * DD;          // 128*16*800 bf16 = 3.3 MB

    int n1 = BB * HH * WW * CC;
    rpe_kernel<<<(n1 + 255) / 256, 256, 0, stream>>>(v, w, out);

    int n2 = NINST * LQ;
    pack_kv<<<(n2 + 255) / 256, 256, 0, stream>>>(k, v, kb, vt);

    dim3 grid(NQT, NH, 16);
    attn_mfma<<<grid, 64, 0, stream>>>(q, kb, vt, out);
}

// Round 4
// 51.294 us; speedup vs baseline: 4.0783x; 1.2827x over previous
//
#include <hip/hip_runtime.h>

typedef __bf16 bf16x8 __attribute__((ext_vector_type(8)));
typedef float f32x16 __attribute__((ext_vector_type(16)));
typedef unsigned u32x2 __attribute__((ext_vector_type(2)));

#define BB 2
#define HH 56
#define WW 56
#define NN 2
#define CC 128
#define NH 8
#define DD 16
#define WSP 7
#define LQ 784           // tokens per window = 56*7*2
#define LP 800           // padded token count (zero-filled 784..799)
#define NQT 25           // Q tiles of 32
#define NKC 25           // K chunks of 32
#define NINST 128        // 16 windows * 8 heads
#define NW 4             // waves per block (K-split factor)

// scale * log2(e) so P = exp2(S) directly
#define QSCALE 0.3606737602222409f

union U2 { __bf16 h[2]; unsigned u; };
union U4 { unsigned u[4]; bf16x8 v; };
union H8 { bf16x8 v; uint4 q; };

// ---------------- Kernel 1: RPE (depthwise conv + self-scaled term) --------
__global__ __launch_bounds__(256) void rpe_kernel(const float* __restrict__ value,
                                                  const float* __restrict__ conv_w,
                                                  float* __restrict__ out) {
    int idx = blockIdx.x * blockDim.x + threadIdx.x; // over B*H*W*C
    if (idx >= BB * HH * WW * CC) return;
    int c = idx & (CC - 1);
    int t = idx >> 7;          // b*H*W + y*W + x
    int x = t % WW;
    int t2 = t / WW;
    int y = t2 % HH;
    int b = t2 / HH;

    float w[9];
#pragma unroll
    for (int k = 0; k < 9; ++k) w[k] = conv_w[c * 9 + k];

    float conv_sum = 0.f;
#pragma unroll
    for (int dy = -1; dy <= 1; ++dy) {
        int yy = y + dy;
        if (yy < 0 || yy >= HH) continue;
#pragma unroll
        for (int dx = -1; dx <= 1; ++dx) {
            int xx = x + dx;
            if (xx < 0 || xx >= WW) continue;
            const float* p = value + (((long)(b * HH + yy) * WW + xx) * NN) * CC + c;
            float vs = p[0] + p[CC];   // sum over n
            conv_sum += w[(dy + 1) * 3 + (dx + 1)] * vs;
        }
    }
    float center = w[4];
    const float* pc = value + (((long)(b * HH + y) * WW + x) * NN) * CC + c;
    float v0 = pc[0], v1 = pc[CC];
    float base = conv_sum - center * (v0 + v1);
    float* po = out + (((long)(b * HH + y) * WW + x) * NN) * CC + c;
    po[0]  = base + center * v0;
    po[CC] = base + center * v1;
}

// ---------------- Kernel 2: pack K (bf16 [inst][tok(800)][16]) and V^T -----
// V^T: bf16 [inst][d][tok padded to 800]. Pad tokens zero-filled.
__global__ __launch_bounds__(256) void pack_kv(const float* __restrict__ k_g,
                                               const float* __restrict__ v_g,
                                               __bf16* __restrict__ kb,
                                               __bf16* __restrict__ vt) {
    int idx = blockIdx.x * blockDim.x + threadIdx.x;
    if (idx >= NINST * LP) return;
    int inst = idx / LP;
    int tok  = idx - inst * LP;

    if (tok >= LQ) {                  // zero pad
        H8 z; z.q = make_uint4(0, 0, 0, 0);
        uint4* kq = (uint4*)kb + (long)idx * 2;
        kq[0] = z.q; kq[1] = z.q;
#pragma unroll
        for (int d = 0; d < 16; ++d)
            vt[((long)inst * 16 + d) * LP + tok] = (__bf16)0.f;
        return;
    }

    int head = inst & 7, win = inst >> 3;
    int b = win >> 3, wj = win & 7;
    int pos = tok >> 1, n = tok & 1;
    int y = pos / WSP, xl = pos - y * WSP;
    long off = ((long)(((b * HH + y) * WW + wj * WSP + xl) * NN + n)) * CC + head * DD;

    float kv[16], vv[16];
    *(float4*)&kv[0]  = *(const float4*)(k_g + off);
    *(float4*)&kv[4]  = *(const float4*)(k_g + off + 4);
    *(float4*)&kv[8]  = *(const float4*)(k_g + off + 8);
    *(float4*)&kv[12] = *(const float4*)(k_g + off + 12);
    *(float4*)&vv[0]  = *(const float4*)(v_g + off);
    *(float4*)&vv[4]  = *(const float4*)(v_g + off + 4);
    *(float4*)&vv[8]  = *(const float4*)(v_g + off + 8);
    *(float4*)&vv[12] = *(const float4*)(v_g + off + 12);

    H8 lo, hi;
#pragma unroll
    for (int i = 0; i < 8; ++i) { lo.v[i] = (__bf16)kv[i]; hi.v[i] = (__bf16)kv[8 + i]; }
    uint4* kq = (uint4*)kb + (long)idx * 2;
    kq[0] = lo.q;
    kq[1] = hi.q;

#pragma unroll
    for (int d = 0; d < 16; ++d)
        vt[((long)inst * 16 + d) * LP + tok] = (__bf16)vv[d];
}

// ---------------- Kernel 3: MFMA flash attention, 4-wave K-split -----------
// Block = 4 waves; wave w owns chunks c = w, w+4, ... Swapped QK^T:
//   S^T = mfma(A=K, B=Q) -> lane owns query col (lane&31); softmax lane-local,
//   NO max-tracking (S bounded, f32 exp safe). O^T = mfma(A=V^T, B=P).
__global__ __launch_bounds__(256) void attn_mfma(const float* __restrict__ q_g,
                                                 const __bf16* __restrict__ kb,
                                                 const __bf16* __restrict__ vt,
                                                 float* __restrict__ out) {
    __shared__ float red[NW][32][18];   // per-wave partials: 16 d + 2 lsum halves

    const int tid  = threadIdx.x;
    const int w    = tid >> 6;
    const int lane = tid & 63;
    const int col  = lane & 31;        // query col / key row / d row
    const int h    = lane >> 5;
    const int dl   = col & 15;
    const int head = blockIdx.y;
    const int win  = blockIdx.z;
    const int inst = win * 8 + head;
    const int qt   = blockIdx.x;
    const int q0   = qt * 32;
    const int myq  = q0 + col;
    const int sib  = myq ^ 1;

    const int myqc = myq < LQ ? myq : LQ - 1;
    const int b = win >> 3, wj = win & 7;
    const int pos = myqc >> 1, n = myqc & 1;
    const int y = pos / WSP, xl = pos - y * WSP;
    const long ooff = ((long)(((b * HH + y) * WW + wj * WSP + xl) * NN + n)) * CC + head * DD;

    // Q fragment (B operand): col=query, k = d = 8h..8h+7; scale*log2e folded
    bf16x8 qfv;
    {
        const float* qp = q_g + ooff + 8 * h;
        float qv[8];
        *(float4*)&qv[0] = *(const float4*)qp;
        *(float4*)&qv[4] = *(const float4*)(qp + 4);
        H8 qq;
#pragma unroll
        for (int i = 0; i < 8; ++i) qq.v[i] = (__bf16)(qv[i] * QSCALE);
        qfv = qq.v;
    }

    f32x16 acc, zv;
#pragma unroll
    for (int i = 0; i < 16; ++i) { acc[i] = 0.f; zv[i] = 0.f; }
    float lsum = 0.f;

    const bf16x8* kp = (const bf16x8*)kb + ((long)inst * LP + w * 32 + col) * 2 + h;
    const __bf16* vp = vt + ((long)inst * 16 + dl) * LP + 8 * h;

    for (int c = w; c < NKC; c += NW) {
        bf16x8 kf = *kp;
        kp += NW * 32 * 2;

        f32x16 st = __builtin_amdgcn_mfma_f32_32x32x16_bf16(kf, qfv, zv, 0, 0, 0);

        float p[16];
        if (c == qt || c == NKC - 1) {  // only these chunks need masking
#pragma unroll
            for (int r = 0; r < 16; ++r) {
                int kr = (r & 3) + 8 * (r >> 2) + 4 * h;
                int gk = c * 32 + kr;
                p[r] = (gk >= LQ || gk == sib) ? 0.f : __builtin_amdgcn_exp2f(st[r]);
            }
        } else {
#pragma unroll
            for (int r = 0; r < 16; ++r) p[r] = __builtin_amdgcn_exp2f(st[r]);
        }
        // 5-deep tree sum instead of 16-deep chain
        float s0 = (p[0] + p[1]) + (p[2] + p[3]);
        float s1 = (p[4] + p[5]) + (p[6] + p[7]);
        float s2 = (p[8] + p[9]) + (p[10] + p[11]);
        float s3 = (p[12] + p[13]) + (p[14] + p[15]);
        lsum += (s0 + s1) + (s2 + s3);

        // pack P to bf16 pairs; pk[b2] covers keys 8*b2+4h..+3 of this chunk
        unsigned pk[4][2];
#pragma unroll
        for (int b2 = 0; b2 < 4; ++b2) {
            U2 a, bb;
            a.h[0]  = (__bf16)p[4 * b2 + 0];
            a.h[1]  = (__bf16)p[4 * b2 + 1];
            bb.h[0] = (__bf16)p[4 * b2 + 2];
            bb.h[1] = (__bf16)p[4 * b2 + 3];
            pk[b2][0] = a.u;
            pk[b2][1] = bb.u;
        }

#pragma unroll
        for (int t = 0; t < 2; ++t) {
            // B = P fragment: col=query, k = keys 16t+8h+0..7
            U4 pb;
#pragma unroll
            for (int j = 0; j < 2; ++j) {
#if __has_builtin(__builtin_amdgcn_permlane32_swap)
                u32x2 rr = __builtin_amdgcn_permlane32_swap(pk[2 * t][j], pk[2 * t + 1][j], false, false);
                pb.u[j]     = rr[0];
                pb.u[2 + j] = rr[1];
#else
                unsigned swa = __shfl_xor(pk[2 * t][j], 32, 64);
                unsigned swb = __shfl_xor(pk[2 * t + 1][j], 32, 64);
                pb.u[j]     = h ? swb : pk[2 * t][j];
                pb.u[2 + j] = h ? pk[2 * t + 1][j] : swa;
#endif
            }
            bf16x8 vf = *(const bf16x8*)(vp + c * 32 + 16 * t);
            acc = __builtin_amdgcn_mfma_f32_32x32x16_bf16(vf, pb.v, acc, 0, 0, 0);
        }
    }

    // per-wave partials to LDS: d = (r&3)+8*(r>>2)+4h for regs 0..7
#pragma unroll
    for (int r = 0; r < 8; ++r)
        red[w][col][(r & 3) + 8 * (r >> 2) + 4 * h] = acc[r];
    red[w][col][16 + h] = lsum;
    __syncthreads();

    if (w == 0 && myq < LQ) {
        float l = 0.f;
        float o[8];
#pragma unroll
        for (int i = 0; i < 8; ++i) o[i] = 0.f;
#pragma unroll
        for (int ww = 0; ww < NW; ++ww) {
            l += red[ww][col][16] + red[ww][col][17];
#pragma unroll
            for (int i = 0; i < 8; ++i) o[i] += red[ww][col][8 * h + i];
        }
        float inv = 1.f / l;
        float* po = out + ooff + 8 * h;
        float4 r0 = *(float4*)po;
        float4 r1 = *(float4*)(po + 4);
        r0.x += o[0] * inv; r0.y += o[1] * inv; r0.z += o[2] * inv; r0.w += o[3] * inv;
        r1.x += o[4] * inv; r1.y += o[5] * inv; r1.z += o[6] * inv; r1.w += o[7] * inv;
        *(float4*)po = r0;
        *(float4*)(po + 4) = r1;
    }
}

extern "C" void kernel_launch(void* const* d_in, const int* in_sizes, int n_in,
                              void* d_out, int out_size, void* d_ws, size_t ws_size,
                              hipStream_t stream) {
    const float* q = (const float*)d_in[0];
    const float* k = (const float*)d_in[1];
    const float* v = (const float*)d_in[2];
    const float* w = (const float*)d_in[3];
    float* out = (float*)d_out;

    __bf16* kb = (__bf16*)d_ws;                       // 128*800*16 bf16 = 3.28 MB
    __bf16* vt = kb + (long)NINST * LP * DD;          // 128*16*800 bf16 = 3.28 MB

    int n1 = BB * HH * WW * CC;
    rpe_kernel<<<(n1 + 255) / 256, 256, 0, stream>>>(v, w, out);

    int n2 = NINST * LP;
    pack_kv<<<(n2 + 255) / 256, 256, 0, stream>>>(k, v, kb, vt);

    dim3 grid(NQT, NH, 16);
    attn_mfma<<<grid, 256, 0, stream>>>(q, kb, vt, out);
}

// Round 5
// 47.784 us; speedup vs baseline: 4.3779x; 1.0735x over previous
//
#include <hip/hip_runtime.h>

typedef __bf16 bf16x8 __attribute__((ext_vector_type(8)));
typedef float f32x16 __attribute__((ext_vector_type(16)));
typedef unsigned u32x2 __attribute__((ext_vector_type(2)));

#define BB 2
#define HH 56
#define WW 56
#define NN 2
#define CC 128
#define NH 8
#define DD 16
#define WSP 7
#define LQ 784           // tokens per window = 56*7*2
#define LP 800           // padded token count (zero-filled 784..799)
#define NQT 25           // Q tiles of 32
#define NKC 25           // K chunks of 32
#define NINST 128        // 16 windows * 8 heads
#define NW 4             // waves per block (K-split factor)
#define NB_RPE 3136      // 2*56*56*128 / 256
#define NB_PACK 400      // 128*800 / 256

// scale * log2(e) so P = exp2(S) directly
#define QSCALE 0.3606737602222409f

union U2 { __bf16 h[2]; unsigned u; };
union U4 { unsigned u[4]; bf16x8 v; };
union H8 { bf16x8 v; uint4 q; };

// ---------------- Kernel 1: fused RPE + K/V pack ---------------------------
// Blocks [0, NB_RPE): depthwise-conv RPE written to out.
// Blocks [NB_RPE, NB_RPE+NB_PACK): pack K -> bf16 [inst][tok(800)][16] and
// V^T -> bf16 [inst][d][tok(800)]; pad tokens zero-filled.
__global__ __launch_bounds__(256) void prep_kernel(const float* __restrict__ value,
                                                   const float* __restrict__ conv_w,
                                                   const float* __restrict__ k_g,
                                                   float* __restrict__ out,
                                                   __bf16* __restrict__ kb,
                                                   __bf16* __restrict__ vt) {
    const int bx = blockIdx.x;
    const int tid = threadIdx.x;

    if (bx < NB_RPE) {
        int idx = bx * 256 + tid;           // over B*H*W*C (exact)
        int c = idx & (CC - 1);
        int t = idx >> 7;
        int x = t % WW;
        int t2 = t / WW;
        int y = t2 % HH;
        int b = t2 / HH;

        float w[9];
#pragma unroll
        for (int k = 0; k < 9; ++k) w[k] = conv_w[c * 9 + k];

        float conv_sum = 0.f;
#pragma unroll
        for (int dy = -1; dy <= 1; ++dy) {
            int yy = y + dy;
            if (yy < 0 || yy >= HH) continue;
#pragma unroll
            for (int dx = -1; dx <= 1; ++dx) {
                int xx = x + dx;
                if (xx < 0 || xx >= WW) continue;
                const float* p = value + (((long)(b * HH + yy) * WW + xx) * NN) * CC + c;
                float vs = p[0] + p[CC];
                conv_sum += w[(dy + 1) * 3 + (dx + 1)] * vs;
            }
        }
        float center = w[4];
        const float* pc = value + (((long)(b * HH + y) * WW + x) * NN) * CC + c;
        float v0 = pc[0], v1 = pc[CC];
        float base = conv_sum - center * (v0 + v1);
        float* po = out + (((long)(b * HH + y) * WW + x) * NN) * CC + c;
        po[0]  = base + center * v0;
        po[CC] = base + center * v1;
    } else {
        int idx = (bx - NB_RPE) * 256 + tid;   // over NINST*LP (exact)
        int inst = idx / LP;
        int tok  = idx - inst * LP;

        if (tok >= LQ) {                        // zero pad
            H8 z; z.q = make_uint4(0, 0, 0, 0);
            uint4* kq = (uint4*)kb + (long)idx * 2;
            kq[0] = z.q; kq[1] = z.q;
#pragma unroll
            for (int d = 0; d < 16; ++d)
                vt[((long)inst * 16 + d) * LP + tok] = (__bf16)0.f;
            return;
        }

        int head = inst & 7, win = inst >> 3;
        int b = win >> 3, wj = win & 7;
        int pos = tok >> 1, n = tok & 1;
        int y = pos / WSP, xl = pos - y * WSP;
        long off = ((long)(((b * HH + y) * WW + wj * WSP + xl) * NN + n)) * CC + head * DD;

        float kv[16], vv[16];
        *(float4*)&kv[0]  = *(const float4*)(k_g + off);
        *(float4*)&kv[4]  = *(const float4*)(k_g + off + 4);
        *(float4*)&kv[8]  = *(const float4*)(k_g + off + 8);
        *(float4*)&kv[12] = *(const float4*)(k_g + off + 12);
        *(float4*)&vv[0]  = *(const float4*)(value + off);
        *(float4*)&vv[4]  = *(const float4*)(value + off + 4);
        *(float4*)&vv[8]  = *(const float4*)(value + off + 8);
        *(float4*)&vv[12] = *(const float4*)(value + off + 12);

        H8 lo, hi;
#pragma unroll
        for (int i = 0; i < 8; ++i) { lo.v[i] = (__bf16)kv[i]; hi.v[i] = (__bf16)kv[8 + i]; }
        uint4* kq = (uint4*)kb + (long)idx * 2;
        kq[0] = lo.q;
        kq[1] = hi.q;

#pragma unroll
        for (int d = 0; d < 16; ++d)
            vt[((long)inst * 16 + d) * LP + tok] = (__bf16)vv[d];
    }
}

// ---------------- Kernel 2: MFMA flash attention, 4-wave K-split -----------
// Flattened grid with XCD-affinity: all 25 Q-tiles of an instance map to the
// same XCD (bid%8), so its 50KB packed K/V stays in that XCD's L2.
// Swapped QK^T: S^T = mfma(A=K, B=Q) -> lane owns query col; softmax
// lane-local, no max-tracking (S bounded, f32 exp safe). O^T = mfma(V^T, P).
__global__ __launch_bounds__(256) void attn_mfma(const float* __restrict__ q_g,
                                                 const __bf16* __restrict__ kb,
                                                 const __bf16* __restrict__ vt,
                                                 float* __restrict__ out) {
    __shared__ float red[NW][32][18];   // per-wave partials: 16 d + 2 lsum halves

    const int bid  = blockIdx.x;
    const int slot = bid >> 3;              // 0..399
    const int inst = (bid & 7) + 8 * (slot / 25);
    const int qt   = slot % 25;
    const int head = inst & 7;
    const int win  = inst >> 3;

    const int tid  = threadIdx.x;
    const int w    = tid >> 6;
    const int lane = tid & 63;
    const int col  = lane & 31;        // query col / key row / d row
    const int h    = lane >> 5;
    const int dl   = col & 15;
    const int q0   = qt * 32;
    const int myq  = q0 + col;
    const int sib  = myq ^ 1;

    const int myqc = myq < LQ ? myq : LQ - 1;
    const int b = win >> 3, wj = win & 7;
    const int pos = myqc >> 1, n = myqc & 1;
    const int y = pos / WSP, xl = pos - y * WSP;
    const long ooff = ((long)(((b * HH + y) * WW + wj * WSP + xl) * NN + n)) * CC + head * DD;

    // Q fragment (B operand): col=query, k = d = 8h..8h+7; scale*log2e folded
    bf16x8 qfv;
    {
        const float* qp = q_g + ooff + 8 * h;
        float qv[8];
        *(float4*)&qv[0] = *(const float4*)qp;
        *(float4*)&qv[4] = *(const float4*)(qp + 4);
        H8 qq;
#pragma unroll
        for (int i = 0; i < 8; ++i) qq.v[i] = (__bf16)(qv[i] * QSCALE);
        qfv = qq.v;
    }

    f32x16 acc, zv;
#pragma unroll
    for (int i = 0; i < 16; ++i) { acc[i] = 0.f; zv[i] = 0.f; }
    float lsum = 0.f;

    const bf16x8* kpb = (const bf16x8*)kb + ((long)inst * LP + col) * 2 + h;  // + c*64
    const __bf16* vp  = vt + ((long)inst * 16 + dl) * LP + 8 * h;             // + c*32 + 16t

    // software pipeline: preload chunk w
    bf16x8 kf  = kpb[(long)w * 64];
    bf16x8 vf0 = *(const bf16x8*)(vp + w * 32);
    bf16x8 vf1 = *(const bf16x8*)(vp + w * 32 + 16);

    for (int c = w; c < NKC; c += NW) {
        // issue next chunk's loads before the serial exp/pack block
        const int cn = (c + NW < NKC) ? c + NW : c;
        bf16x8 kf_n  = kpb[(long)cn * 64];
        bf16x8 vf0_n = *(const bf16x8*)(vp + cn * 32);
        bf16x8 vf1_n = *(const bf16x8*)(vp + cn * 32 + 16);

        f32x16 st = __builtin_amdgcn_mfma_f32_32x32x16_bf16(kf, qfv, zv, 0, 0, 0);

        float p[16];
        if (c == qt || c == NKC - 1) {  // only these chunks need masking
#pragma unroll
            for (int r = 0; r < 16; ++r) {
                int kr = (r & 3) + 8 * (r >> 2) + 4 * h;
                int gk = c * 32 + kr;
                p[r] = (gk >= LQ || gk == sib) ? 0.f : __builtin_amdgcn_exp2f(st[r]);
            }
        } else {
#pragma unroll
            for (int r = 0; r < 16; ++r) p[r] = __builtin_amdgcn_exp2f(st[r]);
        }
        float s0 = (p[0] + p[1]) + (p[2] + p[3]);
        float s1 = (p[4] + p[5]) + (p[6] + p[7]);
        float s2 = (p[8] + p[9]) + (p[10] + p[11]);
        float s3 = (p[12] + p[13]) + (p[14] + p[15]);
        lsum += (s0 + s1) + (s2 + s3);

        // pack P to bf16 pairs; pk[b2] covers keys 8*b2+4h..+3 of this chunk
        unsigned pk[4][2];
#pragma unroll
        for (int b2 = 0; b2 < 4; ++b2) {
            U2 a, bb;
            a.h[0]  = (__bf16)p[4 * b2 + 0];
            a.h[1]  = (__bf16)p[4 * b2 + 1];
            bb.h[0] = (__bf16)p[4 * b2 + 2];
            bb.h[1] = (__bf16)p[4 * b2 + 3];
            pk[b2][0] = a.u;
            pk[b2][1] = bb.u;
        }

#pragma unroll
        for (int t = 0; t < 2; ++t) {
            U4 pb;
#pragma unroll
            for (int j = 0; j < 2; ++j) {
#if __has_builtin(__builtin_amdgcn_permlane32_swap)
                u32x2 rr = __builtin_amdgcn_permlane32_swap(pk[2 * t][j], pk[2 * t + 1][j], false, false);
                pb.u[j]     = rr[0];
                pb.u[2 + j] = rr[1];
#else
                unsigned swa = __shfl_xor(pk[2 * t][j], 32, 64);
                unsigned swb = __shfl_xor(pk[2 * t + 1][j], 32, 64);
                pb.u[j]     = h ? swb : pk[2 * t][j];
                pb.u[2 + j] = h ? pk[2 * t + 1][j] : swa;
#endif
            }
            bf16x8 vf = t == 0 ? vf0 : vf1;
            acc = __builtin_amdgcn_mfma_f32_32x32x16_bf16(vf, pb.v, acc, 0, 0, 0);
        }
        kf = kf_n; vf0 = vf0_n; vf1 = vf1_n;
    }

    // per-wave partials to LDS: d = (r&3)+8*(r>>2)+4h for regs 0..7
#pragma unroll
    for (int r = 0; r < 8; ++r)
        red[w][col][(r & 3) + 8 * (r >> 2) + 4 * h] = acc[r];
    red[w][col][16 + h] = lsum;
    __syncthreads();

    if (w == 0 && myq < LQ) {
        float l = 0.f;
        float o[8];
#pragma unroll
        for (int i = 0; i < 8; ++i) o[i] = 0.f;
#pragma unroll
        for (int ww = 0; ww < NW; ++ww) {
            l += red[ww][col][16] + red[ww][col][17];
#pragma unroll
            for (int i = 0; i < 8; ++i) o[i] += red[ww][col][8 * h + i];
        }
        float inv = 1.f / l;
        float* po = out + ooff + 8 * h;
        float4 r0 = *(float4*)po;
        float4 r1 = *(float4*)(po + 4);
        r0.x += o[0] * inv; r0.y += o[1] * inv; r0.z += o[2] * inv; r0.w += o[3] * inv;
        r1.x += o[4] * inv; r1.y += o[5] * inv; r1.z += o[6] * inv; r1.w += o[7] * inv;
        *(float4*)po = r0;
        *(float4*)(po + 4) = r1;
    }
}

extern "C" void kernel_launch(void* const* d_in, const int* in_sizes, int n_in,
                              void* d_out, int out_size, void* d_ws, size_t ws_size,
                              hipStream_t stream) {
    const float* q = (const float*)d_in[0];
    const float* k = (const float*)d_in[1];
    const float* v = (const float*)d_in[2];
    const float* w = (const float*)d_in[3];
    float* out = (float*)d_out;

    __bf16* kb = (__bf16*)d_ws;                       // 128*800*16 bf16 = 3.28 MB
    __bf16* vt = kb + (long)NINST * LP * DD;          // 128*16*800 bf16 = 3.28 MB

    prep_kernel<<<NB_RPE + NB_PACK, 256, 0, stream>>>(v, w, k, out, kb, vt);

    attn_mfma<<<NQT * NH * 16, 256, 0, stream>>>(q, kb, vt, out);
}